// Round 7
// baseline (309.408 us; speedup 1.0000x reference)
//
#include <hip/hip_runtime.h>
#include <stdint.h>

#define DEVI __device__ __forceinline__

typedef __attribute__((ext_vector_type(8))) short bf16x8;
typedef __attribute__((ext_vector_type(4))) float f32x4;
typedef unsigned short u16;
typedef unsigned int u32;

#define TT 2049           // T+1
#define BH 32             // B*H
#define MPAD 8320         // 65*128
#define MREAL 8196        // 4*2049
#define NQ 8192           // 4*N_QKV
#define KDIM 256
#define VTP 2112          // padded t-stride for V^T

#define SBAR() __builtin_amdgcn_s_barrier()
#define MEMFENCE() asm volatile("" ::: "memory")
#define VMCNT(n) asm volatile("s_waitcnt vmcnt(" #n ")" ::: "memory")

DEVI u16 f2bf(float f) {
    union { float f; u32 u; } v; v.f = f;
    u32 r = v.u + 0x7FFF + ((v.u >> 16) & 1);
    return (u16)(r >> 16);
}
DEVI float bf2f(u16 h) {
    union { u32 u; float f; } v; v.u = ((u32)h) << 16;
    return v.f;
}

#define GLD16(src, lds) __builtin_amdgcn_global_load_lds( \
    (const __attribute__((address_space(1))) void*)(src), \
    (__attribute__((address_space(3))) void*)(lds), 16, 0, 0)

// ---------------- conversion kernels (x4 vectorized) ----------------
__global__ void k_conv_x0(const float* __restrict__ x, const float* __restrict__ wsink,
                          u16* __restrict__ x0b) {
    int idx = blockIdx.x * 256 + threadIdx.x;
    if (idx >= MPAD * 64) return;
    int m = idx >> 6, c = (idx & 63) << 2;
    f32x4 v = {0.f, 0.f, 0.f, 0.f};
    if (m < MREAL) {
        int b = m / TT, t = m - b * TT;
        const float* src = (t == 0) ? (wsink + c) : (x + ((size_t)((b << 11) + t - 1) << 8) + c);
        v = *(const f32x4*)src;
    }
    union { u16 h[4]; uint2 u2; } o;
#pragma unroll
    for (int i = 0; i < 4; ++i) o.h[i] = f2bf(v[i]);
    *(uint2*)(x0b + ((size_t)idx << 2)) = o.u2;
}

__global__ void k_conv_bf16(const float* __restrict__ s, u16* __restrict__ d, int n4) {
    int idx = blockIdx.x * 256 + threadIdx.x;
    if (idx >= n4) return;
    f32x4 v = *(const f32x4*)(s + ((size_t)idx << 2));
    union { u16 h[4]; uint2 u2; } o;
#pragma unroll
    for (int i = 0; i < 4; ++i) o.h[i] = f2bf(v[i]);
    *(uint2*)(d + ((size_t)idx << 2)) = o.u2;
}

// ---------------- GEMM1: qkvg = x0 @ Wqkvg^T, scatter epilogue ----------------
// Double-buffered LDS + counted vmcnt (T3/T4): never drain vmcnt(0) in the K-loop.
__global__ __launch_bounds__(256) void k_gemm_qkvg(const u16* __restrict__ A, const u16* __restrict__ Bm,
                                                   u16* __restrict__ Qb, u16* __restrict__ Kb,
                                                   u16* __restrict__ Vt, u16* __restrict__ Gb) {
    __shared__ __align__(16) u16 ldsA[2][128 * 64];
    __shared__ __align__(16) u16 ldsB[2][128 * 64];
    const int tid = threadIdx.x;
    const int l = tid & 63, w = tid >> 6;
    const int row0 = blockIdx.x * 128, col0 = blockIdx.y * 128;
    const int mbase = (w >> 1) * 64, nbase = (w & 1) * 64;
    f32x4 acc[4][4];
    const f32x4 zero = {0.f, 0.f, 0.f, 0.f};
#pragma unroll
    for (int i = 0; i < 4; ++i)
#pragma unroll
        for (int j = 0; j < 4; ++j) acc[i][j] = zero;

    auto STAGE = [&](int kt, int bufi) {
#pragma unroll
        for (int it = 0; it < 4; ++it) {
            int lin = (it * 256 + tid) * 16;
            int r = lin >> 7;
            int cb = lin & 127;
            int scb = cb ^ ((r & 7) << 4);
            const char* sa = (const char*)(A + (size_t)(row0 + r) * KDIM + kt) + scb;
            const char* sb = (const char*)(Bm + (size_t)(col0 + r) * KDIM + kt) + scb;
            GLD16(sa, (char*)&ldsA[bufi][0] + it * 4096 + w * 1024);
            GLD16(sb, (char*)&ldsB[bufi][0] + it * 4096 + w * 1024);
        }
    };

    STAGE(0, 0);
    int buf = 0;
    const int NT = KDIM / 64;
    for (int jt = 0; jt < NT; ++jt) {
        if (jt + 1 < NT) { STAGE((jt + 1) * 64, buf ^ 1); VMCNT(8); }
        else             { VMCNT(0); }
        SBAR(); MEMFENCE();
#pragma unroll
        for (int kk = 0; kk < 64; kk += 32) {
            bf16x8 af[4], bfr[4];
            int cbyte = (kk + ((l >> 4) << 3)) * 2;
#pragma unroll
            for (int mi = 0; mi < 4; ++mi) {
                int rr = mbase + mi * 16 + (l & 15);
                af[mi] = *(const bf16x8*)((const char*)&ldsA[buf][0] + ((rr * 128 + cbyte) ^ ((rr & 7) << 4)));
            }
#pragma unroll
            for (int ni = 0; ni < 4; ++ni) {
                int rr = nbase + ni * 16 + (l & 15);
                bfr[ni] = *(const bf16x8*)((const char*)&ldsB[buf][0] + ((rr * 128 + cbyte) ^ ((rr & 7) << 4)));
            }
#pragma unroll
            for (int mi = 0; mi < 4; ++mi)
#pragma unroll
                for (int ni = 0; ni < 4; ++ni)
                    acc[mi][ni] = __builtin_amdgcn_mfma_f32_16x16x32_bf16(af[mi], bfr[ni], acc[mi][ni], 0, 0, 0);
        }
        MEMFENCE(); SBAR();
        buf ^= 1;
    }
#pragma unroll
    for (int mi = 0; mi < 4; ++mi)
#pragma unroll
        for (int ni = 0; ni < 4; ++ni)
#pragma unroll
            for (int r = 0; r < 4; ++r) {
                int grow = row0 + mbase + mi * 16 + ((l >> 4) << 2) + r;
                if (grow >= MREAL) continue;
                int gcol = col0 + nbase + ni * 16 + (l & 15);
                int b = grow / TT, t = grow - b * TT;
                int h = gcol >> 10, c = gcol & 1023;
                int ty = c >> 8, d = c & 255;
                int bh = b * 8 + h;
                u16 val = f2bf(acc[mi][ni][r]);
                if (ty == 0)      Qb[((size_t)(bh * TT + t) << 8) + d] = val;
                else if (ty == 1) Kb[((size_t)(bh * TT + t) << 8) + d] = val;
                else if (ty == 2) Vt[(size_t)(bh * 256 + d) * VTP + t] = val;
                else              Gb[((size_t)(bh * TT + t) << 8) + d] = val;
            }
}

// ---------------- RoPE + RMSNorm (in place on Q,K), one wave per row ----------------
// Q additionally pre-scaled by 1/16 (the attention score scale) so k_attn skips it.
__global__ void k_rope_rms(u16* __restrict__ Qb, u16* __restrict__ Kb,
                           const float* __restrict__ cosb, const float* __restrict__ sinb,
                           const float* __restrict__ tao) {
    int wid = blockIdx.x * 4 + (threadIdx.x >> 6);
    int l = threadIdx.x & 63;
    const int NROW = BH * TT;
    if (wid >= 2 * NROW) return;
    u16* buf = (wid < NROW) ? Qb : Kb;
    float tv = (wid < NROW) ? tao[0] * 0.0625f : tao[1];
    int r = (wid < NROW) ? wid : wid - NROW;
    int t = r % TT;
    size_t base = ((size_t)r) << 8;
    int dd = l * 2;
    float x1a = bf2f(buf[base + dd]),       x1b = bf2f(buf[base + dd + 1]);
    float x2a = bf2f(buf[base + dd + 128]), x2b = bf2f(buf[base + dd + 129]);
    float ca = cosb[t * 128 + dd], cb = cosb[t * 128 + dd + 1];
    float sa = sinb[t * 128 + dd], sb = sinb[t * 128 + dd + 1];
    float y1a = x1a * ca + x2a * sa;
    float y1b = x1b * cb + x2b * sb;
    float y2a = -x1a * sa + x2a * ca;
    float y2b = -x1b * sb + x2b * cb;
    float ss = y1a * y1a + y1b * y1b + y2a * y2a + y2b * y2b;
#pragma unroll
    for (int m = 1; m < 64; m <<= 1) ss += __shfl_xor(ss, m, 64);
    float scale = rsqrtf(ss * (1.0f / 256.0f) + 1.1920928955078125e-07f) * tv;
    buf[base + dd]       = f2bf(y1a * scale);
    buf[base + dd + 1]   = f2bf(y1b * scale);
    buf[base + dd + 128] = f2bf(y2a * scale);
    buf[base + dd + 129] = f2bf(y2b * scale);
}

// ---------------- flash attention, causal, 128 q-rows per block, 8 waves ----------------
// Fixed-shift softmax; row-sums via register ones-operand MFMA; double-buffered K+V
// with counted vmcnt + raw barriers (T3/T4) so prefetch loads stay in flight across
// the barrier; P round-trip XOR-swizzled; setprio; bh pinned to one XCD.
__global__ __launch_bounds__(512) void k_attn(const u16* __restrict__ Qb, const u16* __restrict__ Kb,
                                              const u16* __restrict__ Vt, const u16* __restrict__ Gb,
                                              const float* __restrict__ tao,
                                              u16* __restrict__ Y) {
    __shared__ __align__(16) u16 Kt[2][64 * 256];   // 32KB each
    __shared__ __align__(16) u16 Vl[2][256 * 64];   // 32KB each
    __shared__ __align__(16) u16 Plds[8][16 * 64];  // 16KB; total 144KB
    const int tid = threadIdx.x, l = tid & 63, w = tid >> 6;
    const int qt = 15 - (blockIdx.x >> 5);          // heavy tiles first
    const int bh = blockIdx.x & 31;                 // pinned to XCD bh%8
    const int b = bh >> 3, h = bh & 7;
    const int mq0 = qt * 128 + w * 16 + 1;          // q-rows 1..2048
    const size_t qkbase = (size_t)bh * TT * 256;
    const size_t vrow0 = (size_t)bh * 256;
    const float Cs = tao[0] * tao[1] * 16.0f;       // score upper bound (rmsnorm)

    bf16x8 aq[8];
    {
        int mq = mq0 + (l & 15);                    // <= 2048 always
        const u16* qp = Qb + qkbase + ((size_t)mq << 8) + ((l >> 4) << 3);
#pragma unroll
        for (int kk = 0; kk < 8; ++kk) aq[kk] = *(const bf16x8*)(qp + kk * 32);
    }
    bf16x8 vone;
#pragma unroll
    for (int i = 0; i < 8; ++i) vone[i] = (short)0x3F80;   // bf16 1.0
    f32x4 acc[16], accs;
    const f32x4 zero = {0.f, 0.f, 0.f, 0.f};
#pragma unroll
    for (int i = 0; i < 16; ++i) acc[i] = zero;
    accs = zero;

    const int nkv = 2 * qt + 3;

    auto STAGE = [&](int j, int bufi) {
        const int kv0 = j << 6;
#pragma unroll
        for (int it = 0; it < 4; ++it) {
            int lin = (it * 512 + tid) * 16;
            {   // K tile: rows of 512B
                int r = lin >> 9, cbyt = lin & 511;
                int scb = cbyt ^ ((r & 7) << 4);
                int krow = kv0 + r; if (krow > 2048) krow = 2048;
                GLD16((const char*)(Kb + qkbase + ((size_t)krow << 8)) + scb,
                      (char*)&Kt[bufi][0] + it * 8192 + w * 1024);
            }
            {   // V^T tile: rows of 128B
                int vr = lin >> 7, cb = lin & 127;
                int scb = cb ^ ((vr & 7) << 4);
                GLD16((const char*)(Vt + (vrow0 + vr) * VTP + kv0) + scb,
                      (char*)&Vl[bufi][0] + it * 8192 + w * 1024);
            }
        }
    };

    STAGE(0, 0);
    int buf = 0;

    for (int j = 0; j < nkv; ++j) {
        const int kv0 = j << 6;
        if (j + 1 < nkv) { STAGE(j + 1, buf ^ 1); VMCNT(8); }
        else             { VMCNT(0); }
        SBAR(); MEMFENCE();

        if (kv0 <= mq0 + 15) {
            f32x4 s[4];
#pragma unroll
            for (int nf = 0; nf < 4; ++nf) s[nf] = zero;
            __builtin_amdgcn_s_setprio(1);
#pragma unroll
            for (int kk = 0; kk < 8; ++kk) {
                int cbyte = kk * 64 + ((l >> 4) << 4);
#pragma unroll
                for (int nf = 0; nf < 4; ++nf) {
                    int rr = nf * 16 + (l & 15);
                    bf16x8 bk = *(const bf16x8*)((const char*)&Kt[buf][0] + ((rr * 512 + cbyte) ^ ((rr & 7) << 4)));
                    s[nf] = __builtin_amdgcn_mfma_f32_16x16x32_bf16(aq[kk], bk, s[nf], 0, 0, 0);
                }
            }
            __builtin_amdgcn_s_setprio(0);
            const bool needmask = (kv0 + 63 > mq0);
            {   // p = exp(s - C), masked -> 0; write P XOR-swizzled
                char* pwb = (char*)&Plds[w][0];
#pragma unroll
                for (int nf = 0; nf < 4; ++nf)
#pragma unroll
                    for (int r = 0; r < 4; ++r) {
                        float sv = s[nf][r];
                        if (needmask) {
                            int kg = kv0 + nf * 16 + (l & 15);
                            int qg = mq0 + ((l >> 4) << 2) + r;
                            if (kg > qg) sv = -1e30f;
                        }
                        float pv = __expf(sv - Cs);
                        int row = ((l >> 4) << 2) + r;
                        int byte = row * 128 + nf * 32 + (l & 15) * 2;
                        *(u16*)(pwb + (byte ^ ((row & 7) << 4))) = f2bf(pv);
                    }
            }
            {   // P read (swizzled) + PV; ones-operand MFMA accumulates row sums
                const char* prb = (const char*)&Plds[w][0];
                int row = l & 15;
                int b0 = row * 128 + ((l >> 4) << 4);
                bf16x8 ap0 = *(const bf16x8*)(prb + (b0 ^ ((row & 7) << 4)));
                bf16x8 ap1 = *(const bf16x8*)(prb + ((b0 + 64) ^ ((row & 7) << 4)));
                __builtin_amdgcn_s_setprio(1);
#pragma unroll
                for (int df = 0; df < 16; ++df) {
                    int vr = df * 16 + (l & 15);
                    int cbase = vr * 128 + ((l >> 4) << 4);
                    bf16x8 bv0 = *(const bf16x8*)((const char*)&Vl[buf][0] + (cbase ^ ((vr & 7) << 4)));
                    bf16x8 bv1 = *(const bf16x8*)((const char*)&Vl[buf][0] + ((cbase + 64) ^ ((vr & 7) << 4)));
                    acc[df] = __builtin_amdgcn_mfma_f32_16x16x32_bf16(ap0, bv0, acc[df], 0, 0, 0);
                    acc[df] = __builtin_amdgcn_mfma_f32_16x16x32_bf16(ap1, bv1, acc[df], 0, 0, 0);
                }
                accs = __builtin_amdgcn_mfma_f32_16x16x32_bf16(ap0, vone, accs, 0, 0, 0);
                accs = __builtin_amdgcn_mfma_f32_16x16x32_bf16(ap1, vone, accs, 0, 0, 0);
                __builtin_amdgcn_s_setprio(0);
            }
        }
        MEMFENCE(); SBAR();
        buf ^= 1;
    }
#pragma unroll
    for (int r = 0; r < 4; ++r) {
        int mq = mq0 + ((l >> 4) << 2) + r;         // 1..2048 always
        float inv = 1.0f / accs[r];                  // every lane holds its row sum
        const u16* gp = Gb + qkbase + ((size_t)mq << 8) + (l & 15);
        u16* yp = Y + ((size_t)(b * 2048 + mq - 1)) * 2048 + h * 256 + (l & 15);
#pragma unroll
        for (int df = 0; df < 16; ++df) {
            float g = bf2f(gp[df * 16]);
            float sg = 1.0f / (1.0f + __expf(-g));
            yp[df * 16] = f2bf(acc[df][r] * inv * sg);
        }
    }
}

// ---------------- GEMM3: out = Y @ Wout^T (BM=64, BN=128; dbuf + counted vmcnt) ----------------
__global__ __launch_bounds__(256) void k_gemm_out(const u16* __restrict__ A, const u16* __restrict__ Bm,
                                                  float* __restrict__ Cout) {
    __shared__ __align__(16) u16 ldsA[2][64 * 64];
    __shared__ __align__(16) u16 ldsB[2][128 * 64];
    const int tid = threadIdx.x;
    const int l = tid & 63, w = tid >> 6;
    const int row0 = blockIdx.x * 64, col0 = blockIdx.y * 128;
    const int mbase = (w >> 1) * 32, nbase = (w & 1) * 64;
    const int K2 = 2048;
    f32x4 acc[2][4];
    const f32x4 zero = {0.f, 0.f, 0.f, 0.f};
#pragma unroll
    for (int i = 0; i < 2; ++i)
#pragma unroll
        for (int j = 0; j < 4; ++j) acc[i][j] = zero;

    auto STAGE = [&](int kt, int bufi) {
#pragma unroll
        for (int it = 0; it < 2; ++it) {
            int lin = (it * 256 + tid) * 16;
            int r = lin >> 7;
            int cb = lin & 127;
            int scb = cb ^ ((r & 7) << 4);
            const char* sa = (const char*)(A + (size_t)(row0 + r) * K2 + kt) + scb;
            GLD16(sa, (char*)&ldsA[bufi][0] + it * 4096 + w * 1024);
        }
#pragma unroll
        for (int it = 0; it < 4; ++it) {
            int lin = (it * 256 + tid) * 16;
            int r = lin >> 7;
            int cb = lin & 127;
            int scb = cb ^ ((r & 7) << 4);
            const char* sb = (const char*)(Bm + (size_t)(col0 + r) * K2 + kt) + scb;
            GLD16(sb, (char*)&ldsB[bufi][0] + it * 4096 + w * 1024);
        }
    };

    STAGE(0, 0);
    int buf = 0;
    const int NT = K2 / 64;
    for (int jt = 0; jt < NT; ++jt) {
        if (jt + 1 < NT) { STAGE((jt + 1) * 64, buf ^ 1); VMCNT(6); }
        else             { VMCNT(0); }
        SBAR(); MEMFENCE();
#pragma unroll
        for (int kk = 0; kk < 64; kk += 32) {
            bf16x8 af[2], bfr[4];
            int cbyte = (kk + ((l >> 4) << 3)) * 2;
#pragma unroll
            for (int mi = 0; mi < 2; ++mi) {
                int rr = mbase + mi * 16 + (l & 15);
                af[mi] = *(const bf16x8*)((const char*)&ldsA[buf][0] + ((rr * 128 + cbyte) ^ ((rr & 7) << 4)));
            }
#pragma unroll
            for (int ni = 0; ni < 4; ++ni) {
                int rr = nbase + ni * 16 + (l & 15);
                bfr[ni] = *(const bf16x8*)((const char*)&ldsB[buf][0] + ((rr * 128 + cbyte) ^ ((rr & 7) << 4)));
            }
#pragma unroll
            for (int mi = 0; mi < 2; ++mi)
#pragma unroll
                for (int ni = 0; ni < 4; ++ni)
                    acc[mi][ni] = __builtin_amdgcn_mfma_f32_16x16x32_bf16(af[mi], bfr[ni], acc[mi][ni], 0, 0, 0);
        }
        MEMFENCE(); SBAR();
        buf ^= 1;
    }
#pragma unroll
    for (int mi = 0; mi < 2; ++mi)
#pragma unroll
        for (int ni = 0; ni < 4; ++ni)
#pragma unroll
            for (int r = 0; r < 4; ++r) {
                int grow = row0 + mbase + mi * 16 + ((l >> 4) << 2) + r;
                int gcol = col0 + nbase + ni * 16 + (l & 15);
                Cout[(size_t)grow * 256 + gcol] = acc[mi][ni][r];
            }
}

extern "C" void kernel_launch(void* const* d_in, const int* in_sizes, int n_in,
                              void* d_out, int out_size, void* d_ws, size_t ws_size,
                              hipStream_t stream) {
    const float* x     = (const float*)d_in[0];
    const float* cosb  = (const float*)d_in[1];
    const float* sinb  = (const float*)d_in[2];
    const float* wqkvg = (const float*)d_in[3];
    const float* wsink = (const float*)d_in[4];
    const float* wout  = (const float*)d_in[5];
    const float* tao   = (const float*)d_in[6];
    float* out = (float*)d_out;

    char* ws = (char*)d_ws;
    u16* x0b = (u16*)(ws + 0);            // 8320*256*2       = 4,259,840
    u16* wqb = (u16*)(ws + 4259840);      // 8192*256*2       = 4,194,304
    u16* wob = (u16*)(ws + 8454144);      // 256*2048*2       = 1,048,576
    u16* Qb  = (u16*)(ws + 9502720);      // 32*2049*256*2    = 33,570,816
    u16* Kb  = (u16*)(ws + 43073536);     // 33,570,816
    u16* Gb  = (u16*)(ws + 76644352);     // 33,570,816
    u16* Vt  = (u16*)(ws + 110215168);    // 32*256*2112*2    = 34,603,008
    u16* Yb  = (u16*)(ws + 144818176);    // 8192*2048*2      = 33,554,432
    // total 178,372,608 bytes

    k_conv_x0<<<dim3((MPAD * 64 + 255) / 256), 256, 0, stream>>>(x, wsink, x0b);
    k_conv_bf16<<<dim3((NQ * 64 + 255) / 256), 256, 0, stream>>>(wqkvg, wqb, NQ * 64);
    k_conv_bf16<<<dim3((256 * 512 + 255) / 256), 256, 0, stream>>>(wout, wob, 256 * 512);
    k_gemm_qkvg<<<dim3(65, 64), 256, 0, stream>>>(x0b, wqb, Qb, Kb, Vt, Gb);
    k_rope_rms<<<dim3((2 * BH * TT + 3) / 4), 256, 0, stream>>>(Qb, Kb, cosb, sinb, tao);
    k_attn<<<dim3(16 * 32), 512, 0, stream>>>(Qb, Kb, Vt, Gb, tao, Yb);
    k_gemm_out<<<dim3(128, 2), 256, 0, stream>>>(Yb, wob, out);
}

// Round 8
// 289.461 us; speedup vs baseline: 1.0689x; 1.0689x over previous
//
#include <hip/hip_runtime.h>
#include <stdint.h>

#define DEVI __device__ __forceinline__

typedef __attribute__((ext_vector_type(8))) short bf16x8;
typedef __attribute__((ext_vector_type(4))) float f32x4;
typedef unsigned short u16;
typedef unsigned int u32;

#define TT 2049           // T+1
#define BH 32             // B*H
#define MPAD 8320         // 65*128
#define MREAL 8196        // 4*2049
#define NQ 8192           // 4*N_QKV
#define KDIM 256
#define VTP 2112          // padded t-stride for V^T

#define SBAR() __builtin_amdgcn_s_barrier()
#define MEMFENCE() asm volatile("" ::: "memory")
#define VMCNT(n) asm volatile("s_waitcnt vmcnt(" #n ")" ::: "memory")
#define LGKMCNT0() asm volatile("s_waitcnt lgkmcnt(0)" ::: "memory")

DEVI u16 f2bf(float f) {
    union { float f; u32 u; } v; v.f = f;
    u32 r = v.u + 0x7FFF + ((v.u >> 16) & 1);
    return (u16)(r >> 16);
}
DEVI float bf2f(u16 h) {
    union { u32 u; float f; } v; v.u = ((u32)h) << 16;
    return v.f;
}

#define GLD16(src, lds) __builtin_amdgcn_global_load_lds( \
    (const __attribute__((address_space(1))) void*)(src), \
    (__attribute__((address_space(3))) void*)(lds), 16, 0, 0)

// ---------------- conversion kernels (x4 vectorized) ----------------
__global__ void k_conv_x0(const float* __restrict__ x, const float* __restrict__ wsink,
                          u16* __restrict__ x0b) {
    int idx = blockIdx.x * 256 + threadIdx.x;
    if (idx >= MPAD * 64) return;
    int m = idx >> 6, c = (idx & 63) << 2;
    f32x4 v = {0.f, 0.f, 0.f, 0.f};
    if (m < MREAL) {
        int b = m / TT, t = m - b * TT;
        const float* src = (t == 0) ? (wsink + c) : (x + ((size_t)((b << 11) + t - 1) << 8) + c);
        v = *(const f32x4*)src;
    }
    union { u16 h[4]; uint2 u2; } o;
#pragma unroll
    for (int i = 0; i < 4; ++i) o.h[i] = f2bf(v[i]);
    *(uint2*)(x0b + ((size_t)idx << 2)) = o.u2;
}

__global__ void k_conv_bf16(const float* __restrict__ s, u16* __restrict__ d, int n4) {
    int idx = blockIdx.x * 256 + threadIdx.x;
    if (idx >= n4) return;
    f32x4 v = *(const f32x4*)(s + ((size_t)idx << 2));
    union { u16 h[4]; uint2 u2; } o;
#pragma unroll
    for (int i = 0; i < 4; ++i) o.h[i] = f2bf(v[i]);
    *(uint2*)(d + ((size_t)idx << 2)) = o.u2;
}

// ---------------- GEMM1: qkvg = x0 @ Wqkvg^T, scatter epilogue (round-6 form) ----------------
__global__ __launch_bounds__(256) void k_gemm_qkvg(const u16* __restrict__ A, const u16* __restrict__ Bm,
                                                   u16* __restrict__ Qb, u16* __restrict__ Kb,
                                                   u16* __restrict__ Vt, u16* __restrict__ Gb) {
    __shared__ __align__(16) u16 ldsA[128 * 64];
    __shared__ __align__(16) u16 ldsB[128 * 64];
    const int tid = threadIdx.x;
    const int l = tid & 63, w = tid >> 6;
    const int row0 = blockIdx.x * 128, col0 = blockIdx.y * 128;
    const int mbase = (w >> 1) * 64, nbase = (w & 1) * 64;
    f32x4 acc[4][4];
    const f32x4 zero = {0.f, 0.f, 0.f, 0.f};
#pragma unroll
    for (int i = 0; i < 4; ++i)
#pragma unroll
        for (int j = 0; j < 4; ++j) acc[i][j] = zero;

    for (int kt = 0; kt < KDIM; kt += 64) {
        __syncthreads();
#pragma unroll
        for (int it = 0; it < 4; ++it) {
            int lin = (it * 256 + tid) * 16;
            int r = lin >> 7;
            int cb = lin & 127;
            int scb = cb ^ ((r & 7) << 4);
            const char* sa = (const char*)(A + (size_t)(row0 + r) * KDIM + kt) + scb;
            const char* sb = (const char*)(Bm + (size_t)(col0 + r) * KDIM + kt) + scb;
            GLD16(sa, (char*)ldsA + it * 4096 + w * 1024);
            GLD16(sb, (char*)ldsB + it * 4096 + w * 1024);
        }
        __syncthreads();
#pragma unroll
        for (int kk = 0; kk < 64; kk += 32) {
            bf16x8 af[4], bfr[4];
            int cbyte = (kk + ((l >> 4) << 3)) * 2;
#pragma unroll
            for (int mi = 0; mi < 4; ++mi) {
                int rr = mbase + mi * 16 + (l & 15);
                af[mi] = *(const bf16x8*)((const char*)ldsA + ((rr * 128 + cbyte) ^ ((rr & 7) << 4)));
            }
#pragma unroll
            for (int ni = 0; ni < 4; ++ni) {
                int rr = nbase + ni * 16 + (l & 15);
                bfr[ni] = *(const bf16x8*)((const char*)ldsB + ((rr * 128 + cbyte) ^ ((rr & 7) << 4)));
            }
#pragma unroll
            for (int mi = 0; mi < 4; ++mi)
#pragma unroll
                for (int ni = 0; ni < 4; ++ni)
                    acc[mi][ni] = __builtin_amdgcn_mfma_f32_16x16x32_bf16(af[mi], bfr[ni], acc[mi][ni], 0, 0, 0);
        }
    }
#pragma unroll
    for (int mi = 0; mi < 4; ++mi)
#pragma unroll
        for (int ni = 0; ni < 4; ++ni)
#pragma unroll
            for (int r = 0; r < 4; ++r) {
                int grow = row0 + mbase + mi * 16 + ((l >> 4) << 2) + r;
                if (grow >= MREAL) continue;
                int gcol = col0 + nbase + ni * 16 + (l & 15);
                int b = grow / TT, t = grow - b * TT;
                int h = gcol >> 10, c = gcol & 1023;
                int ty = c >> 8, d = c & 255;
                int bh = b * 8 + h;
                u16 val = f2bf(acc[mi][ni][r]);
                if (ty == 0)      Qb[((size_t)(bh * TT + t) << 8) + d] = val;
                else if (ty == 1) Kb[((size_t)(bh * TT + t) << 8) + d] = val;
                else if (ty == 2) Vt[(size_t)(bh * 256 + d) * VTP + t] = val;
                else              Gb[((size_t)(bh * TT + t) << 8) + d] = val;
            }
}

// ---------------- RoPE + RMSNorm (in place on Q,K), one wave per row ----------------
__global__ void k_rope_rms(u16* __restrict__ Qb, u16* __restrict__ Kb,
                           const float* __restrict__ cosb, const float* __restrict__ sinb,
                           const float* __restrict__ tao) {
    int wid = blockIdx.x * 4 + (threadIdx.x >> 6);
    int l = threadIdx.x & 63;
    const int NROW = BH * TT;
    if (wid >= 2 * NROW) return;
    u16* buf = (wid < NROW) ? Qb : Kb;
    float tv = (wid < NROW) ? tao[0] * 0.0625f : tao[1];
    int r = (wid < NROW) ? wid : wid - NROW;
    int t = r % TT;
    size_t base = ((size_t)r) << 8;
    int dd = l * 2;
    float x1a = bf2f(buf[base + dd]),       x1b = bf2f(buf[base + dd + 1]);
    float x2a = bf2f(buf[base + dd + 128]), x2b = bf2f(buf[base + dd + 129]);
    float ca = cosb[t * 128 + dd], cb = cosb[t * 128 + dd + 1];
    float sa = sinb[t * 128 + dd], sb = sinb[t * 128 + dd + 1];
    float y1a = x1a * ca + x2a * sa;
    float y1b = x1b * cb + x2b * sb;
    float y2a = -x1a * sa + x2a * ca;
    float y2b = -x1b * sb + x2b * cb;
    float ss = y1a * y1a + y1b * y1b + y2a * y2a + y2b * y2b;
#pragma unroll
    for (int m = 1; m < 64; m <<= 1) ss += __shfl_xor(ss, m, 64);
    float scale = rsqrtf(ss * (1.0f / 256.0f) + 1.1920928955078125e-07f) * tv;
    buf[base + dd]       = f2bf(y1a * scale);
    buf[base + dd + 1]   = f2bf(y1b * scale);
    buf[base + dd + 128] = f2bf(y2a * scale);
    buf[base + dd + 129] = f2bf(y2b * scale);
}

// ---------------- flash attention, causal, 128 q-rows per block, 8 waves ----------------
// Pair-cooperative decomposition to halve LDS-read traffic (the measured bottleneck):
// waves (2j,2j+1) jointly own q-groups {2j,2j+1}. QK^T: wave 2j does kv[0:32),
// wave 2j+1 kv[32:64) for BOTH groups (K B-frags reused across groups). P exchanged
// via LDS (lgkmcnt(0)+barrier). PV: wave 2j does d[0:128), 2j+1 d[128:256) for BOTH
// groups (V B-frags reused across groups). Per-wave ds_read_b128: 66 -> 36.
// Fixed-shift softmax; row-sums via ones-operand MFMA; dbuf K/V with counted vmcnt.
__global__ __launch_bounds__(512) void k_attn(const u16* __restrict__ Qb, const u16* __restrict__ Kb,
                                              const u16* __restrict__ Vt, const u16* __restrict__ Gb,
                                              const float* __restrict__ tao,
                                              u16* __restrict__ Y) {
    __shared__ __align__(16) u16 Kt[2][64 * 256];   // 32KB each
    __shared__ __align__(16) u16 Vl[2][256 * 64];   // 32KB each
    __shared__ __align__(16) u16 Plds[8][16 * 64];  // per-GROUP P tile, swizzled; 16KB
    const int tid = threadIdx.x, l = tid & 63, w = tid >> 6;
    const int qt = 15 - (blockIdx.x >> 5);          // heavy tiles first
    const int bh = blockIdx.x & 31;                 // pinned to XCD bh%8
    const int b = bh >> 3, h = bh & 7;
    const int g0 = (w >> 1) * 2;                    // this pair's first group
    const int kvh = (w & 1) * 32;                   // QK kv-half offset
    const int dh = (w & 1) * 128;                   // PV d-half offset
    const int mq_g0 = qt * 128 + g0 * 16 + 1;       // first q-row of the pair
    const size_t qkbase = (size_t)bh * TT * 256;
    const size_t vrow0 = (size_t)bh * 256;
    const float Cs = tao[0] * tao[1] * 16.0f;       // score upper bound (rmsnorm)

    bf16x8 aq[2][8];                                // Q A-frags for both groups
#pragma unroll
    for (int g = 0; g < 2; ++g) {
        int mq = mq_g0 + g * 16 + (l & 15);
        const u16* qp = Qb + qkbase + ((size_t)mq << 8) + ((l >> 4) << 3);
#pragma unroll
        for (int kk = 0; kk < 8; ++kk) aq[g][kk] = *(const bf16x8*)(qp + kk * 32);
    }
    bf16x8 vone;
#pragma unroll
    for (int i = 0; i < 8; ++i) vone[i] = (short)0x3F80;   // bf16 1.0
    f32x4 acc[2][8], accs[2];                        // [group][df]; d-half per wave
    const f32x4 zero = {0.f, 0.f, 0.f, 0.f};
#pragma unroll
    for (int g = 0; g < 2; ++g) {
#pragma unroll
        for (int i = 0; i < 8; ++i) acc[g][i] = zero;
        accs[g] = zero;
    }

    const int nkv = 2 * qt + 3;

    auto STAGE = [&](int j, int bufi) {
        const int kv0 = j << 6;
#pragma unroll
        for (int it = 0; it < 4; ++it) {
            int lin = (it * 512 + tid) * 16;
            {   // K tile: rows of 512B
                int r = lin >> 9, cbyt = lin & 511;
                int scb = cbyt ^ ((r & 7) << 4);
                int krow = kv0 + r; if (krow > 2048) krow = 2048;
                GLD16((const char*)(Kb + qkbase + ((size_t)krow << 8)) + scb,
                      (char*)&Kt[bufi][0] + it * 8192 + w * 1024);
            }
            {   // V^T tile: rows of 128B
                int vr = lin >> 7, cb = lin & 127;
                int scb = cb ^ ((vr & 7) << 4);
                GLD16((const char*)(Vt + (vrow0 + vr) * VTP + kv0) + scb,
                      (char*)&Vl[bufi][0] + it * 8192 + w * 1024);
            }
        }
    };

    STAGE(0, 0);
    int buf = 0;

    for (int j = 0; j < nkv; ++j) {
        const int kv0 = j << 6;
        if (j + 1 < nkv) { STAGE(j + 1, buf ^ 1); VMCNT(8); }
        else             { VMCNT(0); }
        SBAR(); MEMFENCE();

        const bool active = (kv0 <= mq_g0 + 31);
        if (active) {
            // ---- QK^T: both groups, this wave's kv-half ----
            f32x4 s[2][2];
#pragma unroll
            for (int g = 0; g < 2; ++g) { s[g][0] = zero; s[g][1] = zero; }
            __builtin_amdgcn_s_setprio(1);
#pragma unroll
            for (int kk = 0; kk < 8; ++kk) {
                int cbyte = kk * 64 + ((l >> 4) << 4);
#pragma unroll
                for (int t = 0; t < 2; ++t) {
                    int rr = kvh + t * 16 + (l & 15);
                    bf16x8 bk = *(const bf16x8*)((const char*)&Kt[buf][0] + ((rr * 512 + cbyte) ^ ((rr & 7) << 4)));
#pragma unroll
                    for (int g = 0; g < 2; ++g)
                        s[g][t] = __builtin_amdgcn_mfma_f32_16x16x32_bf16(aq[g][kk], bk, s[g][t], 0, 0, 0);
                }
            }
            __builtin_amdgcn_s_setprio(0);
            // ---- mask + exp + P write (group-local, XOR-swizzled) ----
#pragma unroll
            for (int g = 0; g < 2; ++g) {
                char* pwb = (char*)&Plds[g0 + g][0];
                const bool needmask = (kv0 + kvh + 31 > mq_g0 + g * 16);
#pragma unroll
                for (int t = 0; t < 2; ++t)
#pragma unroll
                    for (int r = 0; r < 4; ++r) {
                        float sv = s[g][t][r];
                        if (needmask) {
                            int kg = kv0 + kvh + t * 16 + (l & 15);
                            int qg = mq_g0 + g * 16 + ((l >> 4) << 2) + r;
                            if (kg > qg) sv = -1e30f;
                        }
                        float pv = __expf(sv - Cs);
                        int row = ((l >> 4) << 2) + r;
                        int byte = row * 128 + (kvh + t * 16 + (l & 15)) * 2;
                        *(u16*)(pwb + (byte ^ ((row & 7) << 4))) = f2bf(pv);
                    }
            }
        }
        LGKMCNT0(); SBAR(); MEMFENCE();       // P exchange within pair

        if (active) {
            // ---- PV: both groups, this wave's d-half; V frags reused across groups ----
            bf16x8 ap[2][2];
#pragma unroll
            for (int g = 0; g < 2; ++g) {
                const char* prb = (const char*)&Plds[g0 + g][0];
                int row = l & 15;
                int b0 = row * 128 + ((l >> 4) << 4);
                ap[g][0] = *(const bf16x8*)(prb + (b0 ^ ((row & 7) << 4)));
                ap[g][1] = *(const bf16x8*)(prb + ((b0 + 64) ^ ((row & 7) << 4)));
            }
            __builtin_amdgcn_s_setprio(1);
#pragma unroll
            for (int df = 0; df < 8; ++df) {
                int vr = dh + df * 16 + (l & 15);
                int cbase = vr * 128 + ((l >> 4) << 4);
                bf16x8 bv0 = *(const bf16x8*)((const char*)&Vl[buf][0] + (cbase ^ ((vr & 7) << 4)));
                bf16x8 bv1 = *(const bf16x8*)((const char*)&Vl[buf][0] + ((cbase + 64) ^ ((vr & 7) << 4)));
#pragma unroll
                for (int g = 0; g < 2; ++g) {
                    acc[g][df] = __builtin_amdgcn_mfma_f32_16x16x32_bf16(ap[g][0], bv0, acc[g][df], 0, 0, 0);
                    acc[g][df] = __builtin_amdgcn_mfma_f32_16x16x32_bf16(ap[g][1], bv1, acc[g][df], 0, 0, 0);
                }
            }
#pragma unroll
            for (int g = 0; g < 2; ++g) {
                accs[g] = __builtin_amdgcn_mfma_f32_16x16x32_bf16(ap[g][0], vone, accs[g], 0, 0, 0);
                accs[g] = __builtin_amdgcn_mfma_f32_16x16x32_bf16(ap[g][1], vone, accs[g], 0, 0, 0);
            }
            __builtin_amdgcn_s_setprio(0);
        }
        MEMFENCE(); SBAR();
        buf ^= 1;
    }
    // ---- epilogue: both groups, this wave's d-half ----
#pragma unroll
    for (int g = 0; g < 2; ++g)
#pragma unroll
        for (int r = 0; r < 4; ++r) {
            int mq = mq_g0 + g * 16 + ((l >> 4) << 2) + r;   // 1..2048 always
            float inv = 1.0f / accs[g][r];
            const u16* gp = Gb + qkbase + ((size_t)mq << 8) + dh + (l & 15);
            u16* yp = Y + ((size_t)(b * 2048 + mq - 1)) * 2048 + h * 256 + dh + (l & 15);
#pragma unroll
            for (int df = 0; df < 8; ++df) {
                float g2 = bf2f(gp[df * 16]);
                float sg = 1.0f / (1.0f + __expf(-g2));
                yp[df * 16] = f2bf(acc[g][df][r] * inv * sg);
            }
        }
}

// ---------------- GEMM3: out = Y @ Wout^T (round-6 form: BM=64, BN=128) ----------------
__global__ __launch_bounds__(256) void k_gemm_out(const u16* __restrict__ A, const u16* __restrict__ Bm,
                                                  float* __restrict__ Cout) {
    __shared__ __align__(16) u16 ldsA[64 * 64];
    __shared__ __align__(16) u16 ldsB[128 * 64];
    const int tid = threadIdx.x;
    const int l = tid & 63, w = tid >> 6;
    const int row0 = blockIdx.x * 64, col0 = blockIdx.y * 128;
    const int mbase = (w >> 1) * 32, nbase = (w & 1) * 64;
    const int K2 = 2048;
    f32x4 acc[2][4];
    const f32x4 zero = {0.f, 0.f, 0.f, 0.f};
#pragma unroll
    for (int i = 0; i < 2; ++i)
#pragma unroll
        for (int j = 0; j < 4; ++j) acc[i][j] = zero;

    for (int kt = 0; kt < K2; kt += 64) {
        __syncthreads();
#pragma unroll
        for (int it = 0; it < 2; ++it) {
            int lin = (it * 256 + tid) * 16;
            int r = lin >> 7;
            int cb = lin & 127;
            int scb = cb ^ ((r & 7) << 4);
            const char* sa = (const char*)(A + (size_t)(row0 + r) * K2 + kt) + scb;
            GLD16(sa, (char*)ldsA + it * 4096 + w * 1024);
        }
#pragma unroll
        for (int it = 0; it < 4; ++it) {
            int lin = (it * 256 + tid) * 16;
            int r = lin >> 7;
            int cb = lin & 127;
            int scb = cb ^ ((r & 7) << 4);
            const char* sb = (const char*)(Bm + (size_t)(col0 + r) * K2 + kt) + scb;
            GLD16(sb, (char*)ldsB + it * 4096 + w * 1024);
        }
        __syncthreads();
#pragma unroll
        for (int kk = 0; kk < 64; kk += 32) {
            bf16x8 af[2], bfr[4];
            int cbyte = (kk + ((l >> 4) << 3)) * 2;
#pragma unroll
            for (int mi = 0; mi < 2; ++mi) {
                int rr = mbase + mi * 16 + (l & 15);
                af[mi] = *(const bf16x8*)((const char*)ldsA + ((rr * 128 + cbyte) ^ ((rr & 7) << 4)));
            }
#pragma unroll
            for (int ni = 0; ni < 4; ++ni) {
                int rr = nbase + ni * 16 + (l & 15);
                bfr[ni] = *(const bf16x8*)((const char*)ldsB + ((rr * 128 + cbyte) ^ ((rr & 7) << 4)));
            }
#pragma unroll
            for (int mi = 0; mi < 2; ++mi)
#pragma unroll
                for (int ni = 0; ni < 4; ++ni)
                    acc[mi][ni] = __builtin_amdgcn_mfma_f32_16x16x32_bf16(af[mi], bfr[ni], acc[mi][ni], 0, 0, 0);
        }
    }
#pragma unroll
    for (int mi = 0; mi < 2; ++mi)
#pragma unroll
        for (int ni = 0; ni < 4; ++ni)
#pragma unroll
            for (int r = 0; r < 4; ++r) {
                int grow = row0 + mbase + mi * 16 + ((l >> 4) << 2) + r;
                int gcol = col0 + nbase + ni * 16 + (l & 15);
                Cout[(size_t)grow * 256 + gcol] = acc[mi][ni][r];
            }
}

extern "C" void kernel_launch(void* const* d_in, const int* in_sizes, int n_in,
                              void* d_out, int out_size, void* d_ws, size_t ws_size,
                              hipStream_t stream) {
    const float* x     = (const float*)d_in[0];
    const float* cosb  = (const float*)d_in[1];
    const float* sinb  = (const float*)d_in[2];
    const float* wqkvg = (const float*)d_in[3];
    const float* wsink = (const float*)d_in[4];
    const float* wout  = (const float*)d_in[5];
    const float* tao   = (const float*)d_in[6];
    float* out = (float*)d_out;

    char* ws = (char*)d_ws;
    u16* x0b = (u16*)(ws + 0);            // 8320*256*2       = 4,259,840
    u16* wqb = (u16*)(ws + 4259840);      // 8192*256*2       = 4,194,304
    u16* wob = (u16*)(ws + 8454144);      // 256*2048*2       = 1,048,576
    u16* Qb  = (u16*)(ws + 9502720);      // 32*2049*256*2    = 33,570,816
    u16* Kb  = (u16*)(ws + 43073536);     // 33,570,816
    u16* Gb  = (u16*)(ws + 76644352);     // 33,570,816
    u16* Vt  = (u16*)(ws + 110215168);    // 32*256*2112*2    = 34,603,008
    u16* Yb  = (u16*)(ws + 144818176);    // 8192*2048*2      = 33,554,432
    // total 178,372,608 bytes

    k_conv_x0<<<dim3((MPAD * 64 + 255) / 256), 256, 0, stream>>>(x, wsink, x0b);
    k_conv_bf16<<<dim3((NQ * 64 + 255) / 256), 256, 0, stream>>>(wqkvg, wqb, NQ * 64);
    k_conv_bf16<<<dim3((256 * 512 + 255) / 256), 256, 0, stream>>>(wout, wob, 256 * 512);
    k_gemm_qkvg<<<dim3(65, 64), 256, 0, stream>>>(x0b, wqb, Qb, Kb, Vt, Gb);
    k_rope_rms<<<dim3((2 * BH * TT + 3) / 4), 256, 0, stream>>>(Qb, Kb, cosb, sinb, tao);
    k_attn<<<dim3(16 * 32), 512, 0, stream>>>(Qb, Kb, Vt, Gb, tao, Yb);
    k_gemm_out<<<dim3(128, 2), 256, 0, stream>>>(Yb, wob, out);
}